// Round 5
// baseline (472.978 us; speedup 1.0000x reference)
//
#include <hip/hip_runtime.h>

static constexpr float SCALE = 0.08838834764831845f; // 1/sqrt(128)

typedef __bf16 bf16;
typedef __bf16 bf16x8 __attribute__((ext_vector_type(8)));
typedef __bf16 bf16x4 __attribute__((ext_vector_type(4)));
typedef float  f32x4  __attribute__((ext_vector_type(4)));

#define MFMA16(a, b, c) __builtin_amdgcn_mfma_f32_16x16x32_bf16((a), (b), (c), 0, 0, 0)

__device__ inline bf16x8 cvt8(const float4& x, const float4& y) {
  bf16x8 r;
  r[0] = (bf16)x.x; r[1] = (bf16)x.y; r[2] = (bf16)x.z; r[3] = (bf16)x.w;
  r[4] = (bf16)y.x; r[5] = (bf16)y.y; r[6] = (bf16)y.z; r[7] = (bf16)y.w;
  return r;
}

// =====================================================================
// Batched projection GEMM (q,k,v in one launch; blockIdx.y selects).
// sel==0 (q): fp32 qf in [b,h,i,dk]
// sel==1 (k): bf16 k16 in [b,h,i,dk]
// sel==2 (v): bf16 v16 in [b,h,i,dk]
// =====================================================================
__global__ __launch_bounds__(256)
void proj3_mfma(const float* __restrict__ Aq, const float* __restrict__ Ak,
                const float* __restrict__ Av,
                const float* __restrict__ Wq, const float* __restrict__ Wk,
                const float* __restrict__ Wv,
                const float* __restrict__ bq, const float* __restrict__ bk,
                const float* __restrict__ bv,
                float* __restrict__ qf,
                bf16* __restrict__ k16, bf16* __restrict__ v16)
{
  const int sel = blockIdx.y;
  const float* A    = sel == 0 ? Aq : (sel == 1 ? Ak : Av);
  const float* W    = sel == 0 ? Wq : (sel == 1 ? Wk : Wv);
  const float* bias = sel == 0 ? bq : (sel == 1 ? bk : bv);
  bf16* Cb          = sel == 1 ? k16 : v16;

  __shared__ bf16 As[64][72];
  __shared__ bf16 Bs[64][72];
  const int t = threadIdx.x;
  const int m0 = (blockIdx.x >> 4) << 6;
  const int n0 = (blockIdx.x & 15) << 6;
  const int wave = t >> 6, lane = t & 63;
  const int wr = wave >> 1, wc = wave & 1;
  const int srow = t >> 2, skc = (t & 3) << 4;
  const float* Ap = A + (size_t)(m0 + srow) * 1024 + skc;
  const float* Wp = W + (size_t)(n0 + srow) * 1024 + skc;
  const int fr = lane & 15, kb = (lane >> 4) << 3;
  f32x4 acc[2][2];
#pragma unroll
  for (int i = 0; i < 2; ++i)
#pragma unroll
    for (int j = 0; j < 2; ++j) acc[i][j] = (f32x4){0.f, 0.f, 0.f, 0.f};

  float4 a4[4], w4[4], a4n[4], w4n[4];
#pragma unroll
  for (int u = 0; u < 4; ++u) {
    a4[u] = *(const float4*)(Ap + u * 4);
    w4[u] = *(const float4*)(Wp + u * 4);
  }
  for (int k0 = 0; k0 < 1024; k0 += 64) {
    __syncthreads();
    *(bf16x8*)&As[srow][skc]     = cvt8(a4[0], a4[1]);
    *(bf16x8*)&As[srow][skc + 8] = cvt8(a4[2], a4[3]);
    *(bf16x8*)&Bs[srow][skc]     = cvt8(w4[0], w4[1]);
    *(bf16x8*)&Bs[srow][skc + 8] = cvt8(w4[2], w4[3]);
    __syncthreads();
    if (k0 + 64 < 1024) {
#pragma unroll
      for (int u = 0; u < 4; ++u) {
        a4n[u] = *(const float4*)(Ap + k0 + 64 + u * 4);
        w4n[u] = *(const float4*)(Wp + k0 + 64 + u * 4);
      }
    }
#pragma unroll
    for (int ks = 0; ks < 2; ++ks) {
      bf16x8 af[2], bff[2];
#pragma unroll
      for (int f = 0; f < 2; ++f) {
        af[f]  = *(const bf16x8*)&As[wr * 32 + f * 16 + fr][ks * 32 + kb];
        bff[f] = *(const bf16x8*)&Bs[wc * 32 + f * 16 + fr][ks * 32 + kb];
      }
#pragma unroll
      for (int i = 0; i < 2; ++i)
#pragma unroll
        for (int j = 0; j < 2; ++j)
          acc[i][j] = MFMA16(af[i], bff[j], acc[i][j]);
    }
#pragma unroll
    for (int u = 0; u < 4; ++u) { a4[u] = a4n[u]; w4[u] = w4n[u]; }
  }
  const int lrow = (lane >> 4) << 2, lcol = lane & 15;
#pragma unroll
  for (int i = 0; i < 2; ++i) {
#pragma unroll
    for (int j = 0; j < 2; ++j) {
      const int n = n0 + wc * 32 + j * 16 + lcol;
      const float bvl = bias[n];
#pragma unroll
      for (int r = 0; r < 4; ++r) {
        const int m = m0 + wr * 32 + i * 16 + lrow + r;
        const float val = acc[i][j][r] + bvl;
        const int b = m >> 9, ii = m & 511, h = n >> 7, dk = n & 127;
        const size_t idx = (((size_t)(b * 8 + h) * 512) + ii) * 128 + dk;
        if (sel == 0) qf[idx] = val;
        else          Cb[idx] = (bf16)val;
      }
    }
  }
}

// =====================================================================
// Output projection: Cf[m*1024+n] = A(bf16) @ W^T + bias
// =====================================================================
__global__ __launch_bounds__(256)
void proj_out(const bf16* __restrict__ A, const float* __restrict__ W,
              const float* __restrict__ bias, float* __restrict__ Cf)
{
  __shared__ bf16 As[64][72];
  __shared__ bf16 Bs[64][72];
  const int t = threadIdx.x;
  const int m0 = (blockIdx.x >> 4) << 6;
  const int n0 = (blockIdx.x & 15) << 6;
  const int wave = t >> 6, lane = t & 63;
  const int wr = wave >> 1, wc = wave & 1;
  const int srow = t >> 2, skc = (t & 3) << 4;
  const bf16*  Ap = A + (size_t)(m0 + srow) * 1024 + skc;
  const float* Wp = W + (size_t)(n0 + srow) * 1024 + skc;
  const int fr = lane & 15, kb = (lane >> 4) << 3;
  f32x4 acc[2][2];
#pragma unroll
  for (int i = 0; i < 2; ++i)
#pragma unroll
    for (int j = 0; j < 2; ++j) acc[i][j] = (f32x4){0.f, 0.f, 0.f, 0.f};

  uint4 a0 = *(const uint4*)Ap, a1 = *(const uint4*)(Ap + 8);
  float4 w4[4], w4n[4];
  uint4 a0n, a1n;
#pragma unroll
  for (int u = 0; u < 4; ++u) w4[u] = *(const float4*)(Wp + u * 4);
  for (int k0 = 0; k0 < 1024; k0 += 64) {
    __syncthreads();
    *(uint4*)&As[srow][skc]      = a0;
    *(uint4*)&As[srow][skc + 8]  = a1;
    *(bf16x8*)&Bs[srow][skc]     = cvt8(w4[0], w4[1]);
    *(bf16x8*)&Bs[srow][skc + 8] = cvt8(w4[2], w4[3]);
    __syncthreads();
    if (k0 + 64 < 1024) {
      a0n = *(const uint4*)(Ap + k0 + 64);
      a1n = *(const uint4*)(Ap + k0 + 72);
#pragma unroll
      for (int u = 0; u < 4; ++u)
        w4n[u] = *(const float4*)(Wp + k0 + 64 + u * 4);
    }
#pragma unroll
    for (int ks = 0; ks < 2; ++ks) {
      bf16x8 af[2], bff[2];
#pragma unroll
      for (int f = 0; f < 2; ++f) {
        af[f]  = *(const bf16x8*)&As[wr * 32 + f * 16 + fr][ks * 32 + kb];
        bff[f] = *(const bf16x8*)&Bs[wc * 32 + f * 16 + fr][ks * 32 + kb];
      }
#pragma unroll
      for (int i = 0; i < 2; ++i)
#pragma unroll
        for (int j = 0; j < 2; ++j)
          acc[i][j] = MFMA16(af[i], bff[j], acc[i][j]);
    }
    a0 = a0n; a1 = a1n;
#pragma unroll
    for (int u = 0; u < 4; ++u) w4[u] = w4n[u];
  }
  const int lrow = (lane >> 4) << 2, lcol = lane & 15;
#pragma unroll
  for (int i = 0; i < 2; ++i) {
#pragma unroll
    for (int j = 0; j < 2; ++j) {
      const int n = n0 + wc * 32 + j * 16 + lcol;
      const float bvl = bias[n];
#pragma unroll
      for (int r = 0; r < 4; ++r) {
        const int m = m0 + wr * 32 + i * 16 + lrow + r;
        Cf[(size_t)m * 1024 + n] = acc[i][j][r] + bvl;
      }
    }
  }
}

// =====================================================================
// attn_mega: one block per (b,i).  Everything between projections:
//  phase 1: s[h][j] = q[b,h,i,:].k[b,h,j,:] + q[b,h,i,:].rk[b,i,j,:]
//           (rk streamed from HBM, k16 from L2, q fp32 in LDS)
//  phase 2: softmax((s*SCALE masked) * factor) in LDS (fp32 p)
//  phase 3: x[h,d] = sum_j p[h,j]*(v16[h,j,d] + rv[j,d])  -> bf16
// =====================================================================
__global__ __launch_bounds__(256)
void attn_mega(const float* __restrict__ qf, const bf16* __restrict__ k16,
               const bf16* __restrict__ v16, const float* __restrict__ rk,
               const float* __restrict__ rv, const int* __restrict__ mask,
               const float* __restrict__ g, bf16* __restrict__ xb16)
{
  const int bi = blockIdx.x, b = bi >> 9, i = bi & 511;
  __shared__ float rel[8][516];
  __shared__ float red[4][8][128];          // phase-3 reduce; aliases qs
  float (*qs)[144] = (float(*)[144])&red[0][0][0];
  const int t = threadIdx.x;

  // phase 0: q row -> LDS (fp32)
  {
    const int h = t >> 5, d0 = (t & 31) << 2;
    const int sub2 = d0 >> 5, dd = d0 & 31;
    const float4 qv = *(const float4*)&qf[(((size_t)(b * 8 + h) * 512) + i) * 128 + d0];
    *(float4*)&qs[h][sub2 * 36 + dd] = qv;
  }
  __syncthreads();

  // phase 1: combined qk + rel-k dots
  const int jj = t >> 2, sub = t & 3;
  for (int jp = 0; jp < 512; jp += 64) {
    const int j = jp + jj;
    const float* rkp = rk + ((size_t)bi * 512 + j) * 128 + sub * 32;
    float rvl[32];
#pragma unroll
    for (int u = 0; u < 8; ++u)
      *(float4*)&rvl[u * 4] = *(const float4*)&rkp[u * 4];
    const bf16* kb0 = k16 + (((size_t)(b * 8) * 512) + j) * 128 + sub * 32;
    float acc[8];
#pragma unroll
    for (int h = 0; h < 8; ++h) {
      const bf16* kp = kb0 + (size_t)h * (512 * 128);
      float kv[32];
#pragma unroll
      for (int u = 0; u < 4; ++u) {
        const bf16x8 kk = *(const bf16x8*)(kp + u * 8);
#pragma unroll
        for (int e = 0; e < 8; ++e) kv[u * 8 + e] = (float)kk[e];
      }
      float a = 0.f;
#pragma unroll
      for (int d4 = 0; d4 < 8; ++d4) {
        const float4 qv = *(const float4*)&qs[h][sub * 36 + (d4 << 2)];
        a = fmaf(qv.x, rvl[d4 * 4 + 0], a);
        a = fmaf(qv.y, rvl[d4 * 4 + 1], a);
        a = fmaf(qv.z, rvl[d4 * 4 + 2], a);
        a = fmaf(qv.w, rvl[d4 * 4 + 3], a);
        a = fmaf(qv.x, kv[d4 * 4 + 0], a);
        a = fmaf(qv.y, kv[d4 * 4 + 1], a);
        a = fmaf(qv.z, kv[d4 * 4 + 2], a);
        a = fmaf(qv.w, kv[d4 * 4 + 3], a);
      }
      acc[h] = a;
    }
#pragma unroll
    for (int h = 0; h < 8; ++h) {
      acc[h] += __shfl_xor(acc[h], 1);
      acc[h] += __shfl_xor(acc[h], 2);
    }
    const int h0 = sub << 1;
    rel[h0][j]     = acc[h0];
    rel[h0 + 1][j] = acc[h0 + 1];
  }
  __syncthreads();

  // phase 2: scale/mask/factor + softmax, p kept fp32 in rel[][]
  {
    const int h = t >> 5, ln = t & 31;
    const int* mrow = mask + ((size_t)(b * 512 + i)) * 512;
    const float* grow = g + (b * 8 + h) * 512;
    const float gi = grow[i];
    float s[16];
    float mx = -3.402823466e+38f;
#pragma unroll
    for (int k = 0; k < 16; ++k) {
      const int j = ln + (k << 5);
      float sv = rel[h][j] * SCALE;
      if (mrow[j] == 0) sv = -1.0e9f;
      const float fac = (j >= i) ? gi : grow[j];
      sv *= fac;
      s[k] = sv;
      mx = fmaxf(mx, sv);
    }
#pragma unroll
    for (int off = 16; off > 0; off >>= 1) mx = fmaxf(mx, __shfl_xor(mx, off));
    float sum = 0.f;
#pragma unroll
    for (int k = 0; k < 16; ++k) { const float e = __expf(s[k] - mx); s[k] = e; sum += e; }
#pragma unroll
    for (int off = 16; off > 0; off >>= 1) sum += __shfl_xor(sum, off);
    const float inv = 1.f / sum;
#pragma unroll
    for (int k = 0; k < 16; ++k) rel[h][ln + (k << 5)] = s[k] * inv;
  }
  __syncthreads();

  // phase 3: x = p . (v + rv); rv streamed, v16 from L2
  const int gq = t >> 5, ln3 = t & 31, d0 = ln3 << 2;
  f32x4 acc3[8];
#pragma unroll
  for (int h = 0; h < 8; ++h) acc3[h] = (f32x4){0.f, 0.f, 0.f, 0.f};
  const float* rp = rv + (size_t)bi * 512 * 128 + d0;
  const bf16* vb0 = v16 + ((size_t)(b * 8) * 512) * 128 + d0;
  for (int j = gq; j < 512; j += 8) {
    const float4 rr = *(const float4*)&rp[(size_t)j * 128];
#pragma unroll
    for (int h = 0; h < 8; ++h) {
      const bf16x4 vv = *(const bf16x4*)(vb0 + ((size_t)h * 512 + j) * 128);
      const float w = rel[h][j];
      acc3[h][0] = fmaf(w, rr.x + (float)vv[0], acc3[h][0]);
      acc3[h][1] = fmaf(w, rr.y + (float)vv[1], acc3[h][1]);
      acc3[h][2] = fmaf(w, rr.z + (float)vv[2], acc3[h][2]);
      acc3[h][3] = fmaf(w, rr.w + (float)vv[3], acc3[h][3]);
    }
  }
  // cross-group reduction: combine lane pairs (gq, gq^1) within wave
#pragma unroll
  for (int h = 0; h < 8; ++h) {
#pragma unroll
    for (int e = 0; e < 4; ++e) acc3[h][e] += __shfl_xor(acc3[h][e], 32);
  }
  const int wv = t >> 6;
  if ((t & 63) < 32) {
#pragma unroll
    for (int h = 0; h < 8; ++h)
      *(f32x4*)&red[wv][h][d0] = acc3[h];
  }
  __syncthreads();
  {
    const int h = t >> 5, dd = (t & 31) << 2;
    f32x4 r = (f32x4){0.f, 0.f, 0.f, 0.f};
#pragma unroll
    for (int w2 = 0; w2 < 4; ++w2) {
      const f32x4 v = *(const f32x4*)&red[w2][h][dd];
      r[0] += v[0]; r[1] += v[1]; r[2] += v[2]; r[3] += v[3];
    }
    bf16x4 o;
#pragma unroll
    for (int e = 0; e < 4; ++e) o[e] = (bf16)r[e];
    *(bf16x4*)&xb16[((size_t)(b * 512 + i)) * 1024 + h * 128 + dd] = o;
  }
}

// =====================================================================
// sep / gating / loss kernel (single block).
// =====================================================================
__global__ __launch_bounds__(256)
void sep_kernel(const float* __restrict__ qb, const float* __restrict__ hw,
                const int* __restrict__ sep_id, const float* __restrict__ hreg,
                float* __restrict__ g, float* __restrict__ loss_out)
{
  __shared__ float pool[16][4];
  __shared__ float spred[16][4];
  __shared__ float lbuf[16];
  __shared__ int sids[4];
  const int t = threadIdx.x;
  if (t < 4) sids[t] = sep_id[t];
  __syncthreads();
  {
    const int dot = t >> 2, sub = t & 3;
    const int bh = dot >> 2, n = dot & 3;
    const int b = bh >> 3, h = bh & 7;
    const int row = sids[n];
    const float* qp = qb + (((size_t)(b * 8 + h) * 512) + row) * 128 + sub * 32;
    const float* wp = hw + h * 128 + sub * 32;
    float s = 0.f;
#pragma unroll
    for (int dd = 0; dd < 32; ++dd) s = fmaf(qp[dd], wp[dd], s);
    s += __shfl_xor(s, 1);
    s += __shfl_xor(s, 2);
    if (sub == 0) { pool[bh][n] = s; }
  }
  __syncthreads();
  if (t < 16) {
    float pv[4];
#pragma unroll
    for (int n = 0; n < 4; ++n) pv[n] = pool[t][n];
    float mx = fmaxf(fmaxf(pv[0], pv[1]), fmaxf(pv[2], pv[3]));
    float sum = 0.f;
#pragma unroll
    for (int n = 0; n < 4; ++n) { pv[n] = expf(pv[n] - mx); sum += pv[n]; }
    const float inv = 1.f / sum;
    float maxp = 0.f, l2 = 0.f;
#pragma unroll
    for (int n = 0; n < 4; ++n) {
      const float pr = pv[n] * inv;
      spred[t][n] = pr;
      maxp = fmaxf(maxp, pr);
      const float tg = hreg[n];
      l2 += tg * (logf(tg) - logf(pr));
    }
    lbuf[t] = (1.f - maxp) / 16.f + l2 / 64.f;
  }
  __syncthreads();
  if (t == 0) {
    float L = 0.f;
#pragma unroll
    for (int r = 0; r < 16; ++r) L += lbuf[r];
    loss_out[0] = L;
  }
  for (int idx = t; idx < 16 * 512; idx += 256) {
    const int bh = idx >> 9, pp = idx & 511;
    float gg = 0.f;
#pragma unroll
    for (int n = 0; n < 4; ++n)
      gg += spred[bh][n] * (pp >= sids[n] ? 1.f : 0.f);
    g[idx] = gg;
  }
}

// =====================================================================
extern "C" void kernel_launch(void* const* d_in, const int* in_sizes, int n_in,
                              void* d_out, int out_size, void* d_ws, size_t ws_size,
                              hipStream_t stream)
{
  const float* query = (const float*)d_in[0];
  const float* key   = (const float*)d_in[1];
  const float* value = (const float*)d_in[2];
  const float* rk    = (const float*)d_in[3];
  const float* rv    = (const float*)d_in[4];
  const int*   mask  = (const int*)d_in[5];
  const int*   sep   = (const int*)d_in[6];
  const float* hreg  = (const float*)d_in[7];
  const float* Wq    = (const float*)d_in[8];
  const float* bq    = (const float*)d_in[9];
  const float* Wk    = (const float*)d_in[10];
  const float* bk    = (const float*)d_in[11];
  const float* Wv    = (const float*)d_in[12];
  const float* bv    = (const float*)d_in[13];
  const float* Wo    = (const float*)d_in[14];
  const float* bo    = (const float*)d_in[15];
  const float* hw    = (const float*)d_in[16];
  float* out = (float*)d_out;

  float* ws  = (float*)d_ws;
  float* qb  = ws;                           // 1,048,576 f32
  float* gb  = qb + 1048576;                 //     8,192 f32
  bf16* k16  = (bf16*)(gb + 8192);           // 1,048,576 bf16
  bf16* v16  = k16 + 1048576;                // 1,048,576 bf16
  bf16* xb16 = v16 + 1048576;                // 1,048,576 bf16

  proj3_mfma<<<dim3(256, 3), 256, 0, stream>>>(query, key, value,
                                               Wq, Wk, Wv, bq, bk, bv,
                                               qb, k16, v16);
  sep_kernel<<<dim3(1), 256, 0, stream>>>(qb, hw, sep, hreg, gb, out + 1048576);
  attn_mega<<<dim3(1024), 256, 0, stream>>>(qb, k16, v16, rk, rv, mask, gb, xb16);
  proj_out<<<dim3(256), 256, 0, stream>>>(xb16, Wo, bo, out);
}

// Round 6
// 232.449 us; speedup vs baseline: 2.0348x; 2.0348x over previous
//
#include <hip/hip_runtime.h>

static constexpr float SCALE = 0.08838834764831845f; // 1/sqrt(128)

typedef __bf16 bf16;
typedef __bf16 bf16x8 __attribute__((ext_vector_type(8)));
typedef float  f32x4  __attribute__((ext_vector_type(4)));

#define MFMA16(a, b, c) __builtin_amdgcn_mfma_f32_16x16x32_bf16((a), (b), (c), 0, 0, 0)

__device__ inline bf16x8 cvt8(const float4& x, const float4& y) {
  bf16x8 r;
  r[0] = (bf16)x.x; r[1] = (bf16)x.y; r[2] = (bf16)x.z; r[3] = (bf16)x.w;
  r[4] = (bf16)y.x; r[5] = (bf16)y.y; r[6] = (bf16)y.z; r[7] = (bf16)y.w;
  return r;
}

// =====================================================================
// Batched projection GEMM (q,k,v in one launch; blockIdx.y selects).
// sel==0 (q): fp32 qf + bf16 q16 in [b,h,i,dk]
// sel==1 (k): bf16 k16 in [b,h,i,dk]
// sel==2 (v): bf16 vt16 TRANSPOSED [b,h,dk,i]
// =====================================================================
__global__ __launch_bounds__(256)
void proj3_mfma(const float* __restrict__ Aq, const float* __restrict__ Ak,
                const float* __restrict__ Av,
                const float* __restrict__ Wq, const float* __restrict__ Wk,
                const float* __restrict__ Wv,
                const float* __restrict__ bq, const float* __restrict__ bk,
                const float* __restrict__ bv,
                float* __restrict__ qf, bf16* __restrict__ q16,
                bf16* __restrict__ k16, bf16* __restrict__ vt16)
{
  const int sel = blockIdx.y;
  const float* A    = sel == 0 ? Aq : (sel == 1 ? Ak : Av);
  const float* W    = sel == 0 ? Wq : (sel == 1 ? Wk : Wv);
  const float* bias = sel == 0 ? bq : (sel == 1 ? bk : bv);

  __shared__ bf16 As[64][72];
  __shared__ bf16 Bs[64][72];
  const int t = threadIdx.x;
  const int m0 = (blockIdx.x >> 4) << 6;
  const int n0 = (blockIdx.x & 15) << 6;
  const int wave = t >> 6, lane = t & 63;
  const int wr = wave >> 1, wc = wave & 1;
  const int srow = t >> 2, skc = (t & 3) << 4;
  const float* Ap = A + (size_t)(m0 + srow) * 1024 + skc;
  const float* Wp = W + (size_t)(n0 + srow) * 1024 + skc;
  const int fr = lane & 15, kb = (lane >> 4) << 3;
  f32x4 acc[2][2];
#pragma unroll
  for (int i = 0; i < 2; ++i)
#pragma unroll
    for (int j = 0; j < 2; ++j) acc[i][j] = (f32x4){0.f, 0.f, 0.f, 0.f};

  float4 a4[4], w4[4], a4n[4], w4n[4];
#pragma unroll
  for (int u = 0; u < 4; ++u) {
    a4[u] = *(const float4*)(Ap + u * 4);
    w4[u] = *(const float4*)(Wp + u * 4);
  }
  for (int k0 = 0; k0 < 1024; k0 += 64) {
    __syncthreads();
    *(bf16x8*)&As[srow][skc]     = cvt8(a4[0], a4[1]);
    *(bf16x8*)&As[srow][skc + 8] = cvt8(a4[2], a4[3]);
    *(bf16x8*)&Bs[srow][skc]     = cvt8(w4[0], w4[1]);
    *(bf16x8*)&Bs[srow][skc + 8] = cvt8(w4[2], w4[3]);
    __syncthreads();
    if (k0 + 64 < 1024) {
#pragma unroll
      for (int u = 0; u < 4; ++u) {
        a4n[u] = *(const float4*)(Ap + k0 + 64 + u * 4);
        w4n[u] = *(const float4*)(Wp + k0 + 64 + u * 4);
      }
    }
#pragma unroll
    for (int ks = 0; ks < 2; ++ks) {
      bf16x8 af[2], bff[2];
#pragma unroll
      for (int f = 0; f < 2; ++f) {
        af[f]  = *(const bf16x8*)&As[wr * 32 + f * 16 + fr][ks * 32 + kb];
        bff[f] = *(const bf16x8*)&Bs[wc * 32 + f * 16 + fr][ks * 32 + kb];
      }
#pragma unroll
      for (int i = 0; i < 2; ++i)
#pragma unroll
        for (int j = 0; j < 2; ++j)
          acc[i][j] = MFMA16(af[i], bff[j], acc[i][j]);
    }
#pragma unroll
    for (int u = 0; u < 4; ++u) { a4[u] = a4n[u]; w4[u] = w4n[u]; }
  }
  const int lrow = (lane >> 4) << 2, lcol = lane & 15;
#pragma unroll
  for (int i = 0; i < 2; ++i) {
#pragma unroll
    for (int j = 0; j < 2; ++j) {
      const int n = n0 + wc * 32 + j * 16 + lcol;
      const float bvl = bias[n];
#pragma unroll
      for (int r = 0; r < 4; ++r) {
        const int m = m0 + wr * 32 + i * 16 + lrow + r;
        const float val = acc[i][j][r] + bvl;
        const int b = m >> 9, ii = m & 511, h = n >> 7, dk = n & 127;
        if (sel == 2) {
          vt16[(((size_t)(b * 8 + h) * 128) + dk) * 512 + ii] = (bf16)val;
        } else {
          const size_t idx = (((size_t)(b * 8 + h) * 512) + ii) * 128 + dk;
          if (sel == 0) { qf[idx] = val; q16[idx] = (bf16)val; }
          else          { k16[idx] = (bf16)val; }
        }
      }
    }
  }
}

// =====================================================================
// qs_fat: blocks 0..1023 = QK^T MFMA (sc = q16 @ k16^T, overwrite);
//         block 1024     = sep/gating/loss.
// =====================================================================
__global__ __launch_bounds__(256)
void qs_fat(const bf16* __restrict__ Q, const bf16* __restrict__ Kb,
            float* __restrict__ scores,
            const float* __restrict__ qf, const float* __restrict__ hw,
            const int* __restrict__ sep_id, const float* __restrict__ hreg,
            float* __restrict__ g, float* __restrict__ loss_out)
{
  __shared__ bf16 As[64][72];
  __shared__ bf16 Bs[64][72];
  __shared__ float pool[16][4];
  __shared__ float spred[16][4];
  __shared__ float lbuf[16];
  __shared__ int sids[4];
  const int t = threadIdx.x;

  if (blockIdx.x >= 1024) {
    // ---- sep/gating/loss ----
    if (t < 4) sids[t] = sep_id[t];
    __syncthreads();
    {
      const int dot = t >> 2, sub = t & 3;
      const int bh = dot >> 2, n = dot & 3;
      const int b = bh >> 3, h = bh & 7;
      const int row = sids[n];
      const float* qp = qf + (((size_t)(b * 8 + h) * 512) + row) * 128 + sub * 32;
      const float* wp = hw + h * 128 + sub * 32;
      float s = 0.f;
#pragma unroll
      for (int dd = 0; dd < 32; ++dd) s = fmaf(qp[dd], wp[dd], s);
      s += __shfl_xor(s, 1);
      s += __shfl_xor(s, 2);
      if (sub == 0) pool[bh][n] = s;
    }
    __syncthreads();
    if (t < 16) {
      float pv[4];
#pragma unroll
      for (int n = 0; n < 4; ++n) pv[n] = pool[t][n];
      float mx = fmaxf(fmaxf(pv[0], pv[1]), fmaxf(pv[2], pv[3]));
      float sum = 0.f;
#pragma unroll
      for (int n = 0; n < 4; ++n) { pv[n] = expf(pv[n] - mx); sum += pv[n]; }
      const float inv = 1.f / sum;
      float maxp = 0.f, l2 = 0.f;
#pragma unroll
      for (int n = 0; n < 4; ++n) {
        const float pr = pv[n] * inv;
        spred[t][n] = pr;
        maxp = fmaxf(maxp, pr);
        const float tg = hreg[n];
        l2 += tg * (logf(tg) - logf(pr));
      }
      lbuf[t] = (1.f - maxp) / 16.f + l2 / 64.f;
    }
    __syncthreads();
    if (t == 0) {
      float L = 0.f;
#pragma unroll
      for (int r = 0; r < 16; ++r) L += lbuf[r];
      loss_out[0] = L;
    }
    for (int idx = t; idx < 16 * 512; idx += 256) {
      const int bh = idx >> 9, pp = idx & 511;
      float gg = 0.f;
#pragma unroll
      for (int n = 0; n < 4; ++n)
        gg += spred[bh][n] * (pp >= sids[n] ? 1.f : 0.f);
      g[idx] = gg;
    }
    return;
  }

  // ---- QK^T MFMA ----
  const int bh = blockIdx.x >> 6, tile = blockIdx.x & 63;
  const bf16* A = Q  + (size_t)bh * (512 * 128);
  const bf16* B = Kb + (size_t)bh * (512 * 128);
  float* C = scores + (size_t)bh * (512 * 512);
  const int m0 = (tile >> 3) << 6, n0 = (tile & 7) << 6;
  const int wave = t >> 6, lane = t & 63;
  const int wr = wave >> 1, wc = wave & 1;
  const int srow = t >> 2, skc = (t & 3) << 4;
  const int fr = lane & 15, kb = (lane >> 4) << 3;
  f32x4 acc[2][2];
#pragma unroll
  for (int i = 0; i < 2; ++i)
#pragma unroll
    for (int j = 0; j < 2; ++j) acc[i][j] = (f32x4){0.f, 0.f, 0.f, 0.f};

  const bf16* ap = A + (size_t)(m0 + srow) * 128 + skc;
  const bf16* bp = B + (size_t)(n0 + srow) * 128 + skc;
  uint4 a0 = *(const uint4*)ap, a1 = *(const uint4*)(ap + 8);
  uint4 b0 = *(const uint4*)bp, b1 = *(const uint4*)(bp + 8);
  for (int k0 = 0; k0 < 128; k0 += 64) {
    __syncthreads();
    *(uint4*)&As[srow][skc]     = a0; *(uint4*)&As[srow][skc + 8] = a1;
    *(uint4*)&Bs[srow][skc]     = b0; *(uint4*)&Bs[srow][skc + 8] = b1;
    __syncthreads();
    if (k0 == 0) {
      a0 = *(const uint4*)(ap + 64); a1 = *(const uint4*)(ap + 72);
      b0 = *(const uint4*)(bp + 64); b1 = *(const uint4*)(bp + 72);
    }
#pragma unroll
    for (int ks = 0; ks < 2; ++ks) {
      bf16x8 af[2], bff[2];
#pragma unroll
      for (int f = 0; f < 2; ++f) {
        af[f]  = *(const bf16x8*)&As[wr * 32 + f * 16 + fr][ks * 32 + kb];
        bff[f] = *(const bf16x8*)&Bs[wc * 32 + f * 16 + fr][ks * 32 + kb];
      }
#pragma unroll
      for (int i = 0; i < 2; ++i)
#pragma unroll
        for (int j = 0; j < 2; ++j)
          acc[i][j] = MFMA16(af[i], bff[j], acc[i][j]);
    }
  }
  const int lrow = (lane >> 4) << 2, lcol = lane & 15;
#pragma unroll
  for (int i = 0; i < 2; ++i)
#pragma unroll
    for (int j = 0; j < 2; ++j)
#pragma unroll
      for (int r = 0; r < 4; ++r) {
        const int m = m0 + wr * 32 + i * 16 + lrow + r;
        const int n = n0 + wc * 32 + j * 16 + lcol;
        C[(size_t)m * 512 + n] = acc[i][j][r];
      }
}

// =====================================================================
// fused_sm: per (b,i) block.
// Phase 1: stream rk[b,i,:,:], rel[h][j] = q[b,h,i,:].rk[b,i,j,:] -> LDS
// Phase 2: s = (sc + rel)*SCALE, mask, *factor, softmax -> pb16
// =====================================================================
__global__ __launch_bounds__(256)
void fused_sm(const float* __restrict__ qf, const float* __restrict__ rk,
              const float* __restrict__ sc, const int* __restrict__ mask,
              const float* __restrict__ g, bf16* __restrict__ pb)
{
  const int bi = blockIdx.x;
  const int b = bi >> 9, i = bi & 511;
  __shared__ float qs[8][144];
  __shared__ float rel[8][516];
  const int t = threadIdx.x;
  {
    const int h = t >> 5, d0 = (t & 31) << 2;
    const int sub2 = d0 >> 5, dd = d0 & 31;
    const float4 qv = *(const float4*)&qf[(((size_t)(b * 8 + h) * 512) + i) * 128 + d0];
    *(float4*)&qs[h][sub2 * 36 + dd] = qv;
  }
  __syncthreads();
  const int jj = t >> 2, sub = t & 3;
  for (int jp = 0; jp < 512; jp += 64) {
    const int j = jp + jj;
    const float* rkp = rk + ((size_t)bi * 512 + j) * 128 + sub * 32;
    float rvl[32];
#pragma unroll
    for (int u = 0; u < 8; ++u)
      *(float4*)&rvl[u * 4] = *(const float4*)&rkp[u * 4];
    float acc[8];
#pragma unroll
    for (int h = 0; h < 8; ++h) acc[h] = 0.f;
#pragma unroll
    for (int d4 = 0; d4 < 8; ++d4) {
#pragma unroll
      for (int h = 0; h < 8; ++h) {
        const float4 qv = *(const float4*)&qs[h][sub * 36 + (d4 << 2)];
        acc[h] = fmaf(qv.x, rvl[d4*4+0], acc[h]);
        acc[h] = fmaf(qv.y, rvl[d4*4+1], acc[h]);
        acc[h] = fmaf(qv.z, rvl[d4*4+2], acc[h]);
        acc[h] = fmaf(qv.w, rvl[d4*4+3], acc[h]);
      }
    }
#pragma unroll
    for (int h = 0; h < 8; ++h) {
      acc[h] += __shfl_xor(acc[h], 1);
      acc[h] += __shfl_xor(acc[h], 2);
    }
    const int h0 = sub << 1;
    rel[h0][j]     = acc[h0];
    rel[h0 + 1][j] = acc[h0 + 1];
  }
  __syncthreads();
  // phase 2: softmax per head row
  const int h = t >> 5, ln = t & 31;
  const float* scrow = sc + (((size_t)(b * 8 + h) * 512) + i) * 512;
  const int* mrow = mask + ((size_t)(b * 512 + i)) * 512;
  const float* grow = g + (b * 8 + h) * 512;
  const float gi = grow[i];
  float s[16];
  float mx = -3.402823466e+38f;
#pragma unroll
  for (int k = 0; k < 16; ++k) {
    const int j = ln + (k << 5);
    float sv = (scrow[j] + rel[h][j]) * SCALE;
    if (mrow[j] == 0) sv = -1.0e9f;
    const float fac = (j >= i) ? gi : grow[j];
    sv *= fac;
    s[k] = sv;
    mx = fmaxf(mx, sv);
  }
#pragma unroll
  for (int off = 16; off > 0; off >>= 1) mx = fmaxf(mx, __shfl_xor(mx, off));
  float sum = 0.f;
#pragma unroll
  for (int k = 0; k < 16; ++k) { const float e = __expf(s[k] - mx); s[k] = e; sum += e; }
#pragma unroll
  for (int off = 16; off > 0; off >>= 1) sum += __shfl_xor(sum, off);
  const float inv = 1.f / sum;
  bf16* prow = pb + (((size_t)(b * 8 + h) * 512) + i) * 512;
#pragma unroll
  for (int k = 0; k < 16; ++k) {
    const int j = ln + (k << 5);
    prow[j] = (bf16)(s[k] * inv);
  }
}

// =====================================================================
// pvrel_fat: blocks 0..255   = PV MFMA  (xb2 = p16 @ vt16, overwrite)
//            blocks 256..1279 = relation_v stream (xa = p . rv)
// proj_out sums xa + xb2.
// =====================================================================
__global__ __launch_bounds__(256)
void pvrel_fat(const bf16* __restrict__ P, const bf16* __restrict__ VT,
               const float* __restrict__ rvg,
               float* __restrict__ xb2, float* __restrict__ xa)
{
  __shared__ float smem[8192];   // relv: ps+red (32 KB); pv: aliased tiles
  const int t = threadIdx.x;

  if (blockIdx.x < 256) {
    // ---- PV MFMA ----
    bf16 (*As)[72] = (bf16(*)[72])&smem[0];
    bf16 (*Bs)[72] = (bf16(*)[72])&smem[2304];   // 64*72*2B = 9216B offset
    const int bh = blockIdx.x >> 4, tile = blockIdx.x & 15;
    const int b = bh >> 3, h = bh & 7;
    const bf16* A = P  + (size_t)bh * (512 * 512);
    const bf16* B = VT + (size_t)bh * (128 * 512);
    float* C = xb2 + (size_t)b * (512 * 1024) + h * 128;
    const int m0 = (tile >> 1) << 6, n0 = (tile & 1) << 6;
    const int wave = t >> 6, lane = t & 63;
    const int wr = wave >> 1, wc = wave & 1;
    const int srow = t >> 2, skc = (t & 3) << 4;
    const int fr = lane & 15, kb = (lane >> 4) << 3;
    f32x4 acc[2][2];
#pragma unroll
    for (int i = 0; i < 2; ++i)
#pragma unroll
      for (int j = 0; j < 2; ++j) acc[i][j] = (f32x4){0.f, 0.f, 0.f, 0.f};

    const bf16* ap = A + (size_t)(m0 + srow) * 512 + skc;
    const bf16* bp = B + (size_t)(n0 + srow) * 512 + skc;
    uint4 a0 = *(const uint4*)ap, a1 = *(const uint4*)(ap + 8);
    uint4 b0 = *(const uint4*)bp, b1 = *(const uint4*)(bp + 8);
    for (int k0 = 0; k0 < 512; k0 += 64) {
      __syncthreads();
      *(uint4*)&As[srow][skc]     = a0; *(uint4*)&As[srow][skc + 8] = a1;
      *(uint4*)&Bs[srow][skc]     = b0; *(uint4*)&Bs[srow][skc + 8] = b1;
      __syncthreads();
      if (k0 + 64 < 512) {
        a0 = *(const uint4*)(ap + k0 + 64); a1 = *(const uint4*)(ap + k0 + 72);
        b0 = *(const uint4*)(bp + k0 + 64); b1 = *(const uint4*)(bp + k0 + 72);
      }
#pragma unroll
      for (int ks = 0; ks < 2; ++ks) {
        bf16x8 af[2], bff[2];
#pragma unroll
        for (int f = 0; f < 2; ++f) {
          af[f]  = *(const bf16x8*)&As[wr * 32 + f * 16 + fr][ks * 32 + kb];
          bff[f] = *(const bf16x8*)&Bs[wc * 32 + f * 16 + fr][ks * 32 + kb];
        }
#pragma unroll
        for (int i = 0; i < 2; ++i)
#pragma unroll
          for (int j = 0; j < 2; ++j)
            acc[i][j] = MFMA16(af[i], bff[j], acc[i][j]);
      }
    }
    const int lrow = (lane >> 4) << 2, lcol = lane & 15;
#pragma unroll
    for (int i = 0; i < 2; ++i)
#pragma unroll
      for (int j = 0; j < 2; ++j)
#pragma unroll
        for (int r = 0; r < 4; ++r) {
          const int m = m0 + wr * 32 + i * 16 + lrow + r;
          const int n = n0 + wc * 32 + j * 16 + lcol;
          C[(size_t)m * 1024 + n] = acc[i][j][r];
        }
    return;
  }

  // ---- relation_v stream ----
  const int bi = blockIdx.x - 256, b = bi >> 9, i = bi & 511;
  float* ps = smem;                      // ps[h][j] stride 520 (first 4160)
  {
    const int h = t >> 5, seg = t & 31;  // 16 j per thread
    const int j0 = seg << 4;
    const bf16x8 v0 = *(const bf16x8*)&P[(((size_t)(b*8 + h) * 512) + i) * 512 + j0];
    const bf16x8 v1 = *(const bf16x8*)&P[(((size_t)(b*8 + h) * 512) + i) * 512 + j0 + 8];
#pragma unroll
    for (int u = 0; u < 8; ++u) ps[h * 520 + j0 + u]     = (float)v0[u];
#pragma unroll
    for (int u = 0; u < 8; ++u) ps[h * 520 + j0 + 8 + u] = (float)v1[u];
  }
  __syncthreads();
  const int gq = t >> 5, ln = t & 31, d0 = ln << 2;
  f32x4 acc[8];
#pragma unroll
  for (int h = 0; h < 8; ++h) acc[h] = (f32x4){0.f, 0.f, 0.f, 0.f};
  const float* rp = rvg + (size_t)bi * 512 * 128 + d0;
  for (int j = gq; j < 512; j += 8) {
    const float4 rr = *(const float4*)&rp[(size_t)j * 128];
#pragma unroll
    for (int h = 0; h < 8; ++h) {
      const float w = ps[h * 520 + j];
      acc[h][0] = fmaf(w, rr.x, acc[h][0]);
      acc[h][1] = fmaf(w, rr.y, acc[h][1]);
      acc[h][2] = fmaf(w, rr.z, acc[h][2]);
      acc[h][3] = fmaf(w, rr.w, acc[h][3]);
    }
  }
  __syncthreads();           // done reading ps; smem becomes red
#pragma unroll
  for (int h = 0; h < 8; ++h)
    *(f32x4*)&smem[((gq << 3) + h) * 128 + d0] = acc[h];
  __syncthreads();
  {
    const int h = t >> 5;
    float4 r = make_float4(0.f, 0.f, 0.f, 0.f);
#pragma unroll
    for (int gg = 0; gg < 8; ++gg) {
      const float4 v = *(const float4*)&smem[((gg << 3) + h) * 128 + d0];
      r.x += v.x; r.y += v.y; r.z += v.z; r.w += v.w;
    }
    *(float4*)&xa[((size_t)(b * 512 + i)) * 1024 + h * 128 + d0] = r;
  }
}

// =====================================================================
// Output projection: Cf[m*1024+n] = (xa + xb2) @ W^T + bias
// =====================================================================
__global__ __launch_bounds__(256)
void proj_out(const float* __restrict__ A, const float* __restrict__ A2,
              const float* __restrict__ W,
              const float* __restrict__ bias, float* __restrict__ Cf)
{
  __shared__ bf16 As[64][72];
  __shared__ bf16 Bs[64][72];
  const int t = threadIdx.x;
  const int m0 = (blockIdx.x >> 4) << 6;
  const int n0 = (blockIdx.x & 15) << 6;
  const int wave = t >> 6, lane = t & 63;
  const int wr = wave >> 1, wc = wave & 1;
  const int srow = t >> 2, skc = (t & 3) << 4;
  const float* Ap  = A  + (size_t)(m0 + srow) * 1024 + skc;
  const float* A2p = A2 + (size_t)(m0 + srow) * 1024 + skc;
  const float* Wp  = W  + (size_t)(n0 + srow) * 1024 + skc;
  const int fr = lane & 15, kb = (lane >> 4) << 3;
  f32x4 acc[2][2];
#pragma unroll
  for (int i = 0; i < 2; ++i)
#pragma unroll
    for (int j = 0; j < 2; ++j) acc[i][j] = (f32x4){0.f, 0.f, 0.f, 0.f};

  float4 a4[4], w4[4], a4n[4], w4n[4];
#pragma unroll
  for (int u = 0; u < 4; ++u) {
    const float4 x1 = *(const float4*)(Ap + u * 4);
    const float4 x2 = *(const float4*)(A2p + u * 4);
    a4[u] = make_float4(x1.x + x2.x, x1.y + x2.y, x1.z + x2.z, x1.w + x2.w);
    w4[u] = *(const float4*)(Wp + u * 4);
  }
  for (int k0 = 0; k0 < 1024; k0 += 64) {
    __syncthreads();
    *(bf16x8*)&As[srow][skc]     = cvt8(a4[0], a4[1]);
    *(bf16x8*)&As[srow][skc + 8] = cvt8(a4[2], a4[3]);
    *(bf16x8*)&Bs[srow][skc]     = cvt8(w4[0], w4[1]);
    *(bf16x8*)&Bs[srow][skc + 8] = cvt8(w4[2], w4[3]);
    __syncthreads();
    if (k0 + 64 < 1024) {
#pragma unroll
      for (int u = 0; u < 4; ++u) {
        const float4 x1 = *(const float4*)(Ap + k0 + 64 + u * 4);
        const float4 x2 = *(const float4*)(A2p + k0 + 64 + u * 4);
        a4n[u] = make_float4(x1.x + x2.x, x1.y + x2.y, x1.z + x2.z, x1.w + x2.w);
        w4n[u] = *(const float4*)(Wp + k0 + 64 + u * 4);
      }
    }
#pragma unroll
    for (int ks = 0; ks < 2; ++ks) {
      bf16x8 af[2], bff[2];
#pragma unroll
      for (int f = 0; f < 2; ++f) {
        af[f]  = *(const bf16x8*)&As[wr * 32 + f * 16 + fr][ks * 32 + kb];
        bff[f] = *(const bf16x8*)&Bs[wc * 32 + f * 16 + fr][ks * 32 + kb];
      }
#pragma unroll
      for (int i = 0; i < 2; ++i)
#pragma unroll
        for (int j = 0; j < 2; ++j)
          acc[i][j] = MFMA16(af[i], bff[j], acc[i][j]);
    }
#pragma unroll
    for (int u = 0; u < 4; ++u) { a4[u] = a4n[u]; w4[u] = w4n[u]; }
  }
  const int lrow = (lane >> 4) << 2, lcol = lane & 15;
#pragma unroll
  for (int i = 0; i < 2; ++i) {
#pragma unroll
    for (int j = 0; j < 2; ++j) {
      const int n = n0 + wc * 32 + j * 16 + lcol;
      const float bvl = bias[n];
#pragma unroll
      for (int r = 0; r < 4; ++r) {
        const int m = m0 + wr * 32 + i * 16 + lrow + r;
        Cf[(size_t)m * 1024 + n] = acc[i][j][r] + bvl;
      }
    }
  }
}

// =====================================================================
extern "C" void kernel_launch(void* const* d_in, const int* in_sizes, int n_in,
                              void* d_out, int out_size, void* d_ws, size_t ws_size,
                              hipStream_t stream)
{
  const float* query = (const float*)d_in[0];
  const float* key   = (const float*)d_in[1];
  const float* value = (const float*)d_in[2];
  const float* rk    = (const float*)d_in[3];
  const float* rv    = (const float*)d_in[4];
  const int*   mask  = (const int*)d_in[5];
  const int*   sep   = (const int*)d_in[6];
  const float* hreg  = (const float*)d_in[7];
  const float* Wq    = (const float*)d_in[8];
  const float* bq    = (const float*)d_in[9];
  const float* Wk    = (const float*)d_in[10];
  const float* bk    = (const float*)d_in[11];
  const float* Wv    = (const float*)d_in[12];
  const float* bv    = (const float*)d_in[13];
  const float* Wo    = (const float*)d_in[14];
  const float* bo    = (const float*)d_in[15];
  const float* hw    = (const float*)d_in[16];
  float* out = (float*)d_out;

  float* ws  = (float*)d_ws;
  float* qb  = ws;                           // 1,048,576 f32
  float* sc  = qb + 1048576;                 // 4,194,304 f32
  float* xa  = sc + 4194304;                 // 1,048,576 f32
  float* xb2 = xa + 1048576;                 // 1,048,576 f32
  float* gb  = xb2 + 1048576;                //     8,192 f32
  bf16* qb16 = (bf16*)(gb + 8192);           // 1,048,576 bf16
  bf16* kb16 = qb16 + 1048576;               // 1,048,576 bf16
  bf16* vt16 = kb16 + 1048576;               // 1,048,576 bf16
  bf16* pb16 = vt16 + 1048576;               // 4,194,304 bf16

  proj3_mfma<<<dim3(256, 3), 256, 0, stream>>>(query, key, value,
                                               Wq, Wk, Wv, bq, bk, bv,
                                               qb, qb16, kb16, vt16);
  qs_fat<<<dim3(1025), 256, 0, stream>>>(qb16, kb16, sc,
                                         qb, hw, sep, hreg, gb, out + 1048576);
  fused_sm<<<dim3(1024), 256, 0, stream>>>(qb, rk, sc, mask, gb, pb16);
  pvrel_fat<<<dim3(1280), 256, 0, stream>>>(pb16, vt16, rv, xb2, xa);
  proj_out<<<dim3(256), 256, 0, stream>>>(xa, xb2, Wo, bo, out);
}